// Round 2
// baseline (576.433 us; speedup 1.0000x reference)
//
#include <hip/hip_runtime.h>

#define S 2048
#define DM 512
#define NH 8
#define HD 64
#define NB 2
#define BH (NB * NH)
#define MROWS (NB * S) // 4096
#define QW (S / 32)    // 64 mask words per row

typedef __bf16 bf16x8 __attribute__((ext_vector_type(8)));
typedef float f32x4 __attribute__((ext_vector_type(4)));

union FragU {
  uint4 u;
  bf16x8 v;
  unsigned short s[8];
};

__device__ __forceinline__ unsigned short f2bf(float x) {
  unsigned u = __float_as_uint(x);
  u += 0x7FFFu + ((u >> 16) & 1u); // RNE
  return (unsigned short)(u >> 16);
}

// ---------------- weight transpose + bf16 convert: Wt[i][n][k] = W_i[k][n] ---
__global__ void k_wtrans(const float* __restrict__ w0, const float* __restrict__ w1,
                         const float* __restrict__ w2, const float* __restrict__ w3,
                         unsigned short* __restrict__ wt) {
  __shared__ float tile[64][65];
  int i = blockIdx.z;
  const float* w = (i == 0) ? w0 : (i == 1) ? w1 : (i == 2) ? w2 : w3;
  int k0 = blockIdx.x * 64;
  int n0 = blockIdx.y * 64;
  int tx = threadIdx.x, ty = threadIdx.y; // (64,4)
  for (int r = ty; r < 64; r += 4)
    tile[r][tx] = w[(size_t)(k0 + r) * DM + n0 + tx];
  __syncthreads();
  unsigned short* o = wt + (size_t)i * DM * DM;
  for (int r = ty; r < 64; r += 4)
    o[(size_t)(n0 + r) * DM + k0 + tx] = f2bf(tile[tx][r]);
}

// ---------------- input fp32 -> bf16 convert (q,k,v activations) -------------
__global__ __launch_bounds__(256) void k_cvt(
    const float* __restrict__ q, const float* __restrict__ k, const float* __restrict__ v,
    unsigned short* __restrict__ oq, unsigned short* __restrict__ ok, unsigned short* __restrict__ ov) {
  int which = blockIdx.y;
  const float* src = (which == 0) ? q : (which == 1) ? k : v;
  unsigned short* dst = (which == 0) ? oq : (which == 1) ? ok : ov;
  size_t t = (size_t)blockIdx.x * 256 + threadIdx.x;
  const float4* s4 = (const float4*)src + t * 2;
  float4 x = s4[0], y = s4[1];
  FragU f;
  f.s[0] = f2bf(x.x); f.s[1] = f2bf(x.y); f.s[2] = f2bf(x.z); f.s[3] = f2bf(x.w);
  f.s[4] = f2bf(y.x); f.s[5] = f2bf(y.y); f.s[6] = f2bf(y.z); f.s[7] = f2bf(y.w);
  *(uint4*)(dst + t * 8) = f.u;
}

// ---------------- mask -> bitpack: mp[b][k][q/32] ----------------------------
__global__ __launch_bounds__(256) void k_maskpack(const int* __restrict__ mask,
                                                  unsigned* __restrict__ mp) {
  size_t gid = (size_t)blockIdx.x * 256 + threadIdx.x;
  int m = mask[gid];
  unsigned long long bal = __ballot(m != 0);
  int lane = threadIdx.x & 63;
  if (lane == 0) {
    uint2 wds = make_uint2((unsigned)bal, (unsigned)(bal >> 32));
    *(uint2*)&mp[gid >> 5] = wds;
  }
}

// ---------------- QKV projection: out_bf16[b][h][s][d] = in @ W + bias -------
__global__ __launch_bounds__(256) void k_proj(
    const unsigned short* __restrict__ inq, const unsigned short* __restrict__ ink,
    const unsigned short* __restrict__ inv, const unsigned short* __restrict__ wt,
    const float* __restrict__ bq, const float* __restrict__ bk, const float* __restrict__ bv,
    unsigned short* __restrict__ oq, unsigned short* __restrict__ ok, unsigned short* __restrict__ ov) {
  int which = blockIdx.z;
  const unsigned short* in = (which == 0) ? inq : (which == 1) ? ink : inv;
  const float* bias = (which == 0) ? bq : (which == 1) ? bk : bv;
  unsigned short* out = (which == 0) ? oq : (which == 1) ? ok : ov;
  const unsigned short* w = wt + (size_t)which * DM * DM;

  int lane = threadIdx.x & 63, wv = threadIdx.x >> 6;
  int m0 = blockIdx.x * 64 + wv * 16;
  int n0 = blockIdx.y * 64;
  int kf = (lane >> 4) * 8;
  int arow = m0 + (lane & 15);

  f32x4 acc[4] = {{0.f, 0.f, 0.f, 0.f}, {0.f, 0.f, 0.f, 0.f},
                  {0.f, 0.f, 0.f, 0.f}, {0.f, 0.f, 0.f, 0.f}};

  for (int kk0 = 0; kk0 < DM; kk0 += 32) {
    FragU af;
    af.u = *(const uint4*)(in + (size_t)arow * DM + kk0 + kf);
#pragma unroll
    for (int nt = 0; nt < 4; nt++) {
      FragU bfr;
      bfr.u = *(const uint4*)(w + (size_t)(n0 + nt * 16 + (lane & 15)) * DM + kk0 + kf);
      acc[nt] = __builtin_amdgcn_mfma_f32_16x16x32_bf16(af.v, bfr.v, acc[nt], 0, 0, 0);
    }
  }
#pragma unroll
  for (int nt = 0; nt < 4; nt++) {
#pragma unroll
    for (int r = 0; r < 4; r++) {
      int row = m0 + (lane >> 4) * 4 + r;   // b*S + s
      int col = n0 + nt * 16 + (lane & 15); // h*64 + d
      float val = acc[nt][r] + bias[col];
      int b = row >> 11, sIdx = row & (S - 1);
      int h = col >> 6, d = col & 63;
      out[(((size_t)(b * NH + h) * S) + sIdx) * HD + d] = f2bf(val);
    }
  }
}

// ---------------- V transpose: vvT[bh][d][s] = vstd[bh][s][d] ----------------
__global__ void k_vtrans(const unsigned short* __restrict__ vin, unsigned short* __restrict__ vout) {
  __shared__ unsigned short tile[64][65];
  int bh = blockIdx.y;
  int s0 = blockIdx.x * 64;
  int tx = threadIdx.x, ty = threadIdx.y; // (64,4)
  const unsigned short* ip = vin + (size_t)bh * S * HD;
  for (int r = ty; r < 64; r += 4)
    tile[r][tx] = ip[(size_t)(s0 + r) * HD + tx];
  __syncthreads();
  unsigned short* op = vout + (size_t)bh * S * HD;
  for (int r = ty; r < 64; r += 4)
    op[(size_t)r * S + s0 + tx] = tile[tx][r];
}

// ---------------- pass 1: Zsum[bh][k] += sum_q exp(logit) (masked -> 0) ------
__global__ __launch_bounds__(256, 4) void k_softmax_z(
    const unsigned short* __restrict__ qq, const unsigned short* __restrict__ kk,
    const unsigned* __restrict__ mp, float* __restrict__ Zsum) {
  int lane = threadIdx.x & 63, w = threadIdx.x >> 6;
  int bh = blockIdx.y;
  int b = bh >> 3;
  int k0 = blockIdx.x * 64 + w * 16;
  int kf = (lane >> 4) * 8;
  int qbase = blockIdx.z * (S / 2);
  int krow_b = k0 + (lane >> 4) * 4;

  const unsigned short* kbase = kk + ((size_t)bh * S + k0 + (lane & 15)) * HD + kf;
  FragU a0, a1;
  a0.u = *(const uint4*)kbase;
  a1.u = *(const uint4*)(kbase + 32);

  const unsigned short* qbaseP = qq + (size_t)bh * S * HD;
  const unsigned* mpb = mp + (size_t)b * S * QW;

  float sum[4] = {0.f, 0.f, 0.f, 0.f};

  for (int q0 = qbase; q0 < qbase + S / 2; q0 += 64) {
    uint2 mw[4];
#pragma unroll
    for (int r = 0; r < 4; r++)
      mw[r] = *(const uint2*)&mpb[(size_t)(krow_b + r) * QW + (q0 >> 5)];
#pragma unroll
    for (int nt = 0; nt < 4; nt++) {
      int qcol = q0 + nt * 16 + (lane & 15);
      const unsigned short* qp = qbaseP + (size_t)qcol * HD + kf;
      FragU b0, b1;
      b0.u = *(const uint4*)qp;
      b1.u = *(const uint4*)(qp + 32);
      f32x4 c = {0.f, 0.f, 0.f, 0.f};
      c = __builtin_amdgcn_mfma_f32_16x16x32_bf16(a0.v, b0.v, c, 0, 0, 0);
      c = __builtin_amdgcn_mfma_f32_16x16x32_bf16(a1.v, b1.v, c, 0, 0, 0);
      unsigned bpos = (unsigned)(nt * 16 + (lane & 15)) & 31u;
#pragma unroll
      for (int r = 0; r < 4; r++) {
        unsigned word = (nt < 2) ? mw[r].x : mw[r].y;
        float e = __expf(c[r] * 0.125f);
        sum[r] += ((word >> bpos) & 1u) ? 0.f : e;
      }
    }
  }
#pragma unroll
  for (int r = 0; r < 4; r++) {
    float s = sum[r];
    s += __shfl_xor(s, 1);
    s += __shfl_xor(s, 2);
    s += __shfl_xor(s, 4);
    s += __shfl_xor(s, 8);
    if ((lane & 15) == 0)
      atomicAdd(&Zsum[(size_t)bh * S + krow_b + r], s);
  }
}

// ---------------- Z -> 1/Z in place ------------------------------------------
__global__ __launch_bounds__(256) void k_invz(float* __restrict__ z) {
  int t = blockIdx.x * 256 + threadIdx.x;
  z[t] = 1.0f / z[t];
}

// ---------------- pass 2: attn write + partial O = A^T V ---------------------
__global__ __launch_bounds__(256, 4) void k_attn(
    const unsigned short* __restrict__ qq, const unsigned short* __restrict__ kk,
    const unsigned short* __restrict__ vvT, const unsigned* __restrict__ mp,
    const float* __restrict__ invZ, float* __restrict__ attn_out,
    float* __restrict__ pO) {
  __shared__ __align__(16) unsigned short pT[64][72]; // [q_local][k_local]
  int lane = threadIdx.x & 63, w = threadIdx.x >> 6;
  int bh = blockIdx.y;
  int b = bh >> 3, h = bh & 7;
  int q0 = blockIdx.x * 64;
  int kbase = blockIdx.z * (S / 2);
  int kf = (lane >> 4) * 8;

  // resident Q B-frags (reused for every k-tile)
  FragU bq[4][2];
#pragma unroll
  for (int nt = 0; nt < 4; nt++) {
    const unsigned short* qp = qq + ((size_t)bh * S + q0 + nt * 16 + (lane & 15)) * HD + kf;
    bq[nt][0].u = *(const uint4*)qp;
    bq[nt][1].u = *(const uint4*)(qp + 32);
  }

  f32x4 o[4] = {{0.f, 0.f, 0.f, 0.f}, {0.f, 0.f, 0.f, 0.f},
                {0.f, 0.f, 0.f, 0.f}, {0.f, 0.f, 0.f, 0.f}};

  const unsigned short* kkb = kk + (size_t)bh * S * HD;
  const unsigned short* vb = vvT + (size_t)bh * HD * S;
  const unsigned* mpb = mp + (size_t)b * S * QW;
  float* ao = attn_out + (size_t)bh * S * S;
  const float* izb = invZ + (size_t)bh * S;
  int q0w = q0 >> 5;

  for (int k0 = kbase; k0 < kbase + S / 2; k0 += 64) {
    int kw = k0 + w * 16;
    int krow_b = kw + (lane >> 4) * 4;
    const unsigned short* kp = kkb + (size_t)(kw + (lane & 15)) * HD + kf;
    FragU a0, a1;
    a0.u = *(const uint4*)kp;
    a1.u = *(const uint4*)(kp + 32);
    float iz[4];
    uint2 mw[4];
#pragma unroll
    for (int r = 0; r < 4; r++) {
      iz[r] = izb[krow_b + r];
      mw[r] = *(const uint2*)&mpb[(size_t)(krow_b + r) * QW + q0w];
    }

#pragma unroll
    for (int nt = 0; nt < 4; nt++) {
      f32x4 c = {0.f, 0.f, 0.f, 0.f};
      c = __builtin_amdgcn_mfma_f32_16x16x32_bf16(a0.v, bq[nt][0].v, c, 0, 0, 0);
      c = __builtin_amdgcn_mfma_f32_16x16x32_bf16(a1.v, bq[nt][1].v, c, 0, 0, 0);
      int ql = nt * 16 + (lane & 15);
      int qcol = q0 + ql;
      unsigned bpos = (unsigned)ql & 31u;
#pragma unroll
      for (int r = 0; r < 4; r++) {
        int kl = w * 16 + (lane >> 4) * 4 + r;
        int krow = k0 + kl;
        unsigned word = (nt < 2) ? mw[r].x : mw[r].y;
        float a = ((word >> bpos) & 1u) ? 0.f : __expf(c[r] * 0.125f) * iz[r];
        ao[(size_t)krow * S + qcol] = a;
        pT[ql][kl] = f2bf(a);
      }
    }
    __syncthreads();

    // O[q][d] += P^T-tile @ V-tile
#pragma unroll
    for (int ks = 0; ks < 2; ks++) {
      FragU af;
      af.u = *(const uint4*)(&pT[w * 16 + (lane & 15)][kf + ks * 32]);
#pragma unroll
      for (int nt = 0; nt < 4; nt++) {
        FragU bfr;
        bfr.u = *(const uint4*)(vb + (size_t)(nt * 16 + (lane & 15)) * S + k0 + kf + ks * 32);
        o[nt] = __builtin_amdgcn_mfma_f32_16x16x32_bf16(af.v, bfr.v, o[nt], 0, 0, 0);
      }
    }
    __syncthreads();
  }

  float* pOz = pO + (size_t)blockIdx.z * MROWS * DM;
#pragma unroll
  for (int nt = 0; nt < 4; nt++) {
#pragma unroll
    for (int r = 0; r < 4; r++) {
      int qg = q0 + w * 16 + (lane >> 4) * 4 + r;
      int col = h * 64 + nt * 16 + (lane & 15);
      pOz[((size_t)b * S + qg) * DM + col] = o[nt][r];
    }
  }
}

// ---------------- sum partial O -> bf16 concat -------------------------------
__global__ __launch_bounds__(256) void k_reduceO(const float* __restrict__ p0,
                                                  const float* __restrict__ p1,
                                                  unsigned short* __restrict__ conc) {
  size_t t = (size_t)blockIdx.x * 256 + threadIdx.x;
  float4 a = ((const float4*)p0)[t];
  float4 b = ((const float4*)p1)[t];
  union { unsigned short s[4]; uint2 u; } o;
  o.s[0] = f2bf(a.x + b.x);
  o.s[1] = f2bf(a.y + b.y);
  o.s[2] = f2bf(a.z + b.z);
  o.s[3] = f2bf(a.w + b.w);
  *(uint2*)(conc + t * 4) = o.u;
}

// ---------------- out projection: out = concat @ Wo + bo ---------------------
__global__ __launch_bounds__(256) void k_outproj(
    const unsigned short* __restrict__ concat, const unsigned short* __restrict__ wt,
    const float* __restrict__ bias, float* __restrict__ out) {
  const unsigned short* w = wt + (size_t)3 * DM * DM;
  int lane = threadIdx.x & 63, wv = threadIdx.x >> 6;
  int m0 = blockIdx.x * 64 + wv * 16;
  int n0 = blockIdx.y * 64;
  int kf = (lane >> 4) * 8;

  f32x4 acc[4] = {{0.f, 0.f, 0.f, 0.f}, {0.f, 0.f, 0.f, 0.f},
                  {0.f, 0.f, 0.f, 0.f}, {0.f, 0.f, 0.f, 0.f}};

  for (int kk0 = 0; kk0 < DM; kk0 += 32) {
    FragU af;
    af.u = *(const uint4*)(concat + (size_t)(m0 + (lane & 15)) * DM + kk0 + kf);
#pragma unroll
    for (int nt = 0; nt < 4; nt++) {
      FragU bfr;
      bfr.u = *(const uint4*)(w + (size_t)(n0 + nt * 16 + (lane & 15)) * DM + kk0 + kf);
      acc[nt] = __builtin_amdgcn_mfma_f32_16x16x32_bf16(af.v, bfr.v, acc[nt], 0, 0, 0);
    }
  }
#pragma unroll
  for (int nt = 0; nt < 4; nt++) {
#pragma unroll
    for (int r = 0; r < 4; r++) {
      int row = m0 + (lane >> 4) * 4 + r;
      int col = n0 + nt * 16 + (lane & 15);
      out[(size_t)row * DM + col] = acc[nt][r] + bias[col];
    }
  }
}

extern "C" void kernel_launch(void* const* d_in, const int* in_sizes, int n_in,
                              void* d_out, int out_size, void* d_ws, size_t ws_size,
                              hipStream_t stream) {
  (void)in_sizes; (void)n_in; (void)out_size; (void)ws_size;
  const float* v    = (const float*)d_in[0];
  const float* q    = (const float*)d_in[1];
  const float* k    = (const float*)d_in[2];
  const int*   mask = (const int*)d_in[3];
  const float* wq_w = (const float*)d_in[4];
  const float* wq_b = (const float*)d_in[5];
  const float* wk_w = (const float*)d_in[6];
  const float* wk_b = (const float*)d_in[7];
  const float* wv_w = (const float*)d_in[8];
  const float* wv_b = (const float*)d_in[9];
  const float* wo_w = (const float*)d_in[10];
  const float* wo_b = (const float*)d_in[11];

  char* ws = (char*)d_ws;
  size_t off = 0;
  auto alloc = [&](size_t bytes) {
    char* p = ws + off;
    off += (bytes + 255) & ~(size_t)255;
    return p;
  };
  unsigned short* wt   = (unsigned short*)alloc((size_t)4 * DM * DM * 2);   // 2 MB
  unsigned short* qbf  = (unsigned short*)alloc((size_t)MROWS * DM * 2);    // 4 MB
  unsigned short* kbf  = (unsigned short*)alloc((size_t)MROWS * DM * 2);    // 4 MB
  unsigned short* vbf  = (unsigned short*)alloc((size_t)MROWS * DM * 2);    // 4 MB
  unsigned short* qq   = (unsigned short*)alloc((size_t)BH * S * HD * 2);   // 4 MB
  unsigned short* kk2  = (unsigned short*)alloc((size_t)BH * S * HD * 2);   // 4 MB
  unsigned short* vstd = (unsigned short*)alloc((size_t)BH * S * HD * 2);   // 4 MB
  unsigned short* vvT  = (unsigned short*)alloc((size_t)BH * S * HD * 2);   // 4 MB
  unsigned*       mp   = (unsigned*)alloc((size_t)NB * S * QW * 4);         // 1 MB
  float*          Zs   = (float*)alloc((size_t)BH * S * 4);                 // 128 KB
  float*          pO   = (float*)alloc((size_t)2 * MROWS * DM * 4);         // 16.8 MB
  unsigned short* conc = (unsigned short*)alloc((size_t)MROWS * DM * 2);    // 4 MB

  float* out_final = (float*)d_out;
  float* out_attn  = (float*)d_out + (size_t)MROWS * DM;

  k_wtrans<<<dim3(8, 8, 4), dim3(64, 4), 0, stream>>>(wq_w, wk_w, wv_w, wo_w, wt);
  k_cvt<<<dim3(1024, 3), 256, 0, stream>>>(q, k, v, qbf, kbf, vbf);
  k_maskpack<<<dim3(32768), 256, 0, stream>>>(mask, mp);
  hipMemsetAsync(Zs, 0, (size_t)BH * S * 4, stream);
  k_proj<<<dim3(64, 8, 3), 256, 0, stream>>>(qbf, kbf, vbf, wt, wq_b, wk_b, wv_b, qq, kk2, vstd);
  k_vtrans<<<dim3(32, 16), dim3(64, 4), 0, stream>>>(vstd, vvT);
  k_softmax_z<<<dim3(32, 16, 2), 256, 0, stream>>>(qq, kk2, mp, Zs);
  k_invz<<<dim3(128), 256, 0, stream>>>(Zs);
  k_attn<<<dim3(32, 16, 2), 256, 0, stream>>>(qq, kk2, vvT, mp, Zs, out_attn, pO);
  k_reduceO<<<dim3(2048), 256, 0, stream>>>(pO, pO + (size_t)MROWS * DM, conc);
  k_outproj<<<dim3(64, 8), 256, 0, stream>>>(conc, wt, wo_b, out_final);
}

// Round 3
// 554.590 us; speedup vs baseline: 1.0394x; 1.0394x over previous
//
#include <hip/hip_runtime.h>

#define S 2048
#define DM 512
#define NH 8
#define HD 64
#define NB 2
#define BH (NB * NH)
#define MROWS (NB * S) // 4096
#define QW (S / 32)    // 64 mask words per row

typedef __bf16 bf16x8 __attribute__((ext_vector_type(8)));
typedef float f32x4 __attribute__((ext_vector_type(4)));

union FragU {
  uint4 u;
  bf16x8 v;
  unsigned short s[8];
};

__device__ __forceinline__ unsigned short f2bf(float x) {
  unsigned u = __float_as_uint(x);
  u += 0x7FFFu + ((u >> 16) & 1u); // RNE
  return (unsigned short)(u >> 16);
}

// ---------------- prep: wtrans + fp32->bf16 cvt + maskpack + Z zero ----------
// grid.x = 256 (wtrans) + 3072 (cvt) + 1024 (maskpack) + 32 (Zs zero) = 4384
__global__ __launch_bounds__(256) void k_prep(
    const float* __restrict__ w0, const float* __restrict__ w1,
    const float* __restrict__ w2, const float* __restrict__ w3,
    unsigned short* __restrict__ wt,
    const float* __restrict__ q, const float* __restrict__ k, const float* __restrict__ v,
    unsigned short* __restrict__ oq, unsigned short* __restrict__ ok, unsigned short* __restrict__ ov,
    const int* __restrict__ mask, unsigned* __restrict__ mp,
    float* __restrict__ Zs) {
  __shared__ float tile[64][65];
  int bid = blockIdx.x;
  int tid = threadIdx.x;
  if (bid < 256) {
    // ---- weight transpose + bf16: wt[i][n][k] = W_i[k][n]
    int i = bid >> 6, rem = bid & 63;
    const float* w = (i == 0) ? w0 : (i == 1) ? w1 : (i == 2) ? w2 : w3;
    int k0 = (rem & 7) * 64, n0 = (rem >> 3) * 64;
    int tx = tid & 63, ty = tid >> 6;
    for (int r = ty; r < 64; r += 4)
      tile[r][tx] = w[(size_t)(k0 + r) * DM + n0 + tx];
    __syncthreads();
    unsigned short* o = wt + (size_t)i * DM * DM;
    for (int r = ty; r < 64; r += 4)
      o[(size_t)(n0 + r) * DM + k0 + tx] = f2bf(tile[tx][r]);
  } else if (bid < 3328) {
    // ---- activation convert
    int b2 = bid - 256;
    int which = b2 >> 10;
    const float* src = (which == 0) ? q : (which == 1) ? k : v;
    unsigned short* dst = (which == 0) ? oq : (which == 1) ? ok : ov;
    size_t t = (size_t)(b2 & 1023) * 256 + tid;
    const float4* s4 = (const float4*)src + t * 2;
    float4 x = s4[0], y = s4[1];
    FragU f;
    f.s[0] = f2bf(x.x); f.s[1] = f2bf(x.y); f.s[2] = f2bf(x.z); f.s[3] = f2bf(x.w);
    f.s[4] = f2bf(y.x); f.s[5] = f2bf(y.y); f.s[6] = f2bf(y.z); f.s[7] = f2bf(y.w);
    *(uint4*)(dst + t * 8) = f.u;
  } else if (bid < 4352) {
    // ---- mask bitpack: mp word t covers mask[t*32 .. t*32+31]
    size_t t = (size_t)(bid - 3328) * 256 + tid;
    const int4* mb = (const int4*)(mask + t * 32);
    unsigned bits = 0;
#pragma unroll
    for (int c = 0; c < 8; c++) {
      int4 m = mb[c];
      bits |= (m.x != 0 ? 1u : 0u) << (c * 4);
      bits |= (m.y != 0 ? 1u : 0u) << (c * 4 + 1);
      bits |= (m.z != 0 ? 1u : 0u) << (c * 4 + 2);
      bits |= (m.w != 0 ? 1u : 0u) << (c * 4 + 3);
    }
    mp[t] = bits;
  } else {
    // ---- zero Z accumulators (32768 floats)
    int t = (bid - 4352) * 256 + tid;
    ((float4*)Zs)[t] = make_float4(0.f, 0.f, 0.f, 0.f);
  }
}

// ---------------- QKV projection (V fused transpose -> vvT[bh][d][s]) -------
__global__ __launch_bounds__(256) void k_proj(
    const unsigned short* __restrict__ inq, const unsigned short* __restrict__ ink,
    const unsigned short* __restrict__ inv, const unsigned short* __restrict__ wt,
    const float* __restrict__ bq, const float* __restrict__ bk, const float* __restrict__ bv,
    unsigned short* __restrict__ oq, unsigned short* __restrict__ ok,
    unsigned short* __restrict__ vvT) {
  __shared__ __align__(16) unsigned short vt[64][72]; // [d][s_local]
  int which = blockIdx.z;
  const unsigned short* in = (which == 0) ? inq : (which == 1) ? ink : inv;
  const float* bias = (which == 0) ? bq : (which == 1) ? bk : bv;
  const unsigned short* w = wt + (size_t)which * DM * DM;

  int lane = threadIdx.x & 63, wv = threadIdx.x >> 6;
  int m0 = blockIdx.x * 64 + wv * 16;
  int n0 = blockIdx.y * 64;
  int kf = (lane >> 4) * 8;
  int arow = m0 + (lane & 15);

  f32x4 acc[4] = {{0.f, 0.f, 0.f, 0.f}, {0.f, 0.f, 0.f, 0.f},
                  {0.f, 0.f, 0.f, 0.f}, {0.f, 0.f, 0.f, 0.f}};

  for (int kk0 = 0; kk0 < DM; kk0 += 32) {
    FragU af;
    af.u = *(const uint4*)(in + (size_t)arow * DM + kk0 + kf);
#pragma unroll
    for (int nt = 0; nt < 4; nt++) {
      FragU bfr;
      bfr.u = *(const uint4*)(w + (size_t)(n0 + nt * 16 + (lane & 15)) * DM + kk0 + kf);
      acc[nt] = __builtin_amdgcn_mfma_f32_16x16x32_bf16(af.v, bfr.v, acc[nt], 0, 0, 0);
    }
  }

  if (which < 2) {
    unsigned short* out = (which == 0) ? oq : ok;
#pragma unroll
    for (int nt = 0; nt < 4; nt++) {
#pragma unroll
      for (int r = 0; r < 4; r++) {
        int row = m0 + (lane >> 4) * 4 + r;   // b*S + s
        int col = n0 + nt * 16 + (lane & 15); // h*64 + d
        float val = acc[nt][r] + bias[col];
        int b = row >> 11, sIdx = row & (S - 1);
        int h = col >> 6, d = col & 63;
        out[(((size_t)(b * NH + h) * S) + sIdx) * HD + d] = f2bf(val);
      }
    }
  } else {
    // stage bias-added bf16 tile transposed in LDS, then write vvT coalesced
#pragma unroll
    for (int nt = 0; nt < 4; nt++) {
#pragma unroll
      for (int r = 0; r < 4; r++) {
        int sl = wv * 16 + (lane >> 4) * 4 + r;
        int dl = nt * 16 + (lane & 15);
        vt[dl][sl] = f2bf(acc[nt][r] + bias[n0 + dl]);
      }
    }
    __syncthreads();
    int b = (blockIdx.x * 64) >> 11;
    int s0l = (blockIdx.x * 64) & (S - 1);
    int h = n0 >> 6;
    unsigned short* op = vvT + (size_t)(b * NH + h) * HD * S;
    int d = threadIdx.x >> 2;
    int sc = (threadIdx.x & 3) * 16;
#pragma unroll
    for (int j = 0; j < 2; j++)
      *(uint4*)&op[(size_t)d * S + s0l + sc + j * 8] = *(uint4*)&vt[d][sc + j * 8];
  }
}

// ---------------- pass 1: Zsum[bh][k] += sum_q exp(logit) (masked -> 0) ------
__global__ __launch_bounds__(256, 4) void k_softmax_z(
    const unsigned short* __restrict__ qq, const unsigned short* __restrict__ kk,
    const unsigned* __restrict__ mp, float* __restrict__ Zsum) {
  int lane = threadIdx.x & 63, w = threadIdx.x >> 6;
  int bh = blockIdx.y;
  int b = bh >> 3;
  int k0 = blockIdx.x * 64 + w * 16;
  int kf = (lane >> 4) * 8;
  int qbase = blockIdx.z * (S / 2);
  int krow_b = k0 + (lane >> 4) * 4;

  const unsigned short* kbase = kk + ((size_t)bh * S + k0 + (lane & 15)) * HD + kf;
  FragU a0, a1;
  a0.u = *(const uint4*)kbase;
  a1.u = *(const uint4*)(kbase + 32);

  const unsigned short* qbaseP = qq + (size_t)bh * S * HD;
  const unsigned* mpb = mp + (size_t)b * S * QW;

  float sum[4] = {0.f, 0.f, 0.f, 0.f};

  for (int q0 = qbase; q0 < qbase + S / 2; q0 += 64) {
    uint2 mw[4];
#pragma unroll
    for (int r = 0; r < 4; r++)
      mw[r] = *(const uint2*)&mpb[(size_t)(krow_b + r) * QW + (q0 >> 5)];
#pragma unroll
    for (int nt = 0; nt < 4; nt++) {
      int qcol = q0 + nt * 16 + (lane & 15);
      const unsigned short* qp = qbaseP + (size_t)qcol * HD + kf;
      FragU b0, b1;
      b0.u = *(const uint4*)qp;
      b1.u = *(const uint4*)(qp + 32);
      f32x4 c = {0.f, 0.f, 0.f, 0.f};
      c = __builtin_amdgcn_mfma_f32_16x16x32_bf16(a0.v, b0.v, c, 0, 0, 0);
      c = __builtin_amdgcn_mfma_f32_16x16x32_bf16(a1.v, b1.v, c, 0, 0, 0);
      unsigned bpos = (unsigned)(nt * 16 + (lane & 15)) & 31u;
#pragma unroll
      for (int r = 0; r < 4; r++) {
        unsigned word = (nt < 2) ? mw[r].x : mw[r].y;
        float e = __expf(c[r] * 0.125f);
        sum[r] += ((word >> bpos) & 1u) ? 0.f : e;
      }
    }
  }
#pragma unroll
  for (int r = 0; r < 4; r++) {
    float s = sum[r];
    s += __shfl_xor(s, 1);
    s += __shfl_xor(s, 2);
    s += __shfl_xor(s, 4);
    s += __shfl_xor(s, 8);
    if ((lane & 15) == 0)
      atomicAdd(&Zsum[(size_t)bh * S + krow_b + r], s);
  }
}

// ---------------- pass 2: attn write + partial O = A^T V ---------------------
__global__ __launch_bounds__(256, 4) void k_attn(
    const unsigned short* __restrict__ qq, const unsigned short* __restrict__ kk,
    const unsigned short* __restrict__ vvT, const unsigned* __restrict__ mp,
    const float* __restrict__ Zsum, float* __restrict__ attn_out,
    float* __restrict__ pO) {
  __shared__ __align__(16) unsigned short pT[2][64][72]; // double-buffered [q_local][k_local]
  int lane = threadIdx.x & 63, w = threadIdx.x >> 6;
  int bh = blockIdx.y;
  int b = bh >> 3, h = bh & 7;
  int q0 = blockIdx.x * 64;
  int kbase = blockIdx.z * (S / 2);
  int kf = (lane >> 4) * 8;

  // resident Q B-frags (reused for every k-tile)
  FragU bq[4][2];
#pragma unroll
  for (int nt = 0; nt < 4; nt++) {
    const unsigned short* qp = qq + ((size_t)bh * S + q0 + nt * 16 + (lane & 15)) * HD + kf;
    bq[nt][0].u = *(const uint4*)qp;
    bq[nt][1].u = *(const uint4*)(qp + 32);
  }

  f32x4 o[4] = {{0.f, 0.f, 0.f, 0.f}, {0.f, 0.f, 0.f, 0.f},
                {0.f, 0.f, 0.f, 0.f}, {0.f, 0.f, 0.f, 0.f}};

  const unsigned short* kkb = kk + (size_t)bh * S * HD;
  const unsigned short* vb = vvT + (size_t)bh * HD * S;
  const unsigned* mpb = mp + (size_t)b * S * QW;
  float* ao = attn_out + (size_t)bh * S * S;
  const float* zb = Zsum + (size_t)bh * S;
  int q0w = q0 >> 5;

  int buf = 0;
  for (int k0 = kbase; k0 < kbase + S / 2; k0 += 64) {
    int kw = k0 + w * 16;
    int krow_b = kw + (lane >> 4) * 4;
    const unsigned short* kp = kkb + (size_t)(kw + (lane & 15)) * HD + kf;
    FragU a0, a1;
    a0.u = *(const uint4*)kp;
    a1.u = *(const uint4*)(kp + 32);
    float iz[4];
    uint2 mw[4];
#pragma unroll
    for (int r = 0; r < 4; r++) {
      iz[r] = 1.0f / zb[krow_b + r];
      mw[r] = *(const uint2*)&mpb[(size_t)(krow_b + r) * QW + q0w];
    }

#pragma unroll
    for (int nt = 0; nt < 4; nt++) {
      f32x4 c = {0.f, 0.f, 0.f, 0.f};
      c = __builtin_amdgcn_mfma_f32_16x16x32_bf16(a0.v, bq[nt][0].v, c, 0, 0, 0);
      c = __builtin_amdgcn_mfma_f32_16x16x32_bf16(a1.v, bq[nt][1].v, c, 0, 0, 0);
      int ql = nt * 16 + (lane & 15);
      int qcol = q0 + ql;
      unsigned bpos = (unsigned)ql & 31u;
#pragma unroll
      for (int r = 0; r < 4; r++) {
        int kl = w * 16 + (lane >> 4) * 4 + r;
        int krow = k0 + kl;
        unsigned word = (nt < 2) ? mw[r].x : mw[r].y;
        float a = ((word >> bpos) & 1u) ? 0.f : __expf(c[r] * 0.125f) * iz[r];
        ao[(size_t)krow * S + qcol] = a;
        pT[buf][ql][kl] = f2bf(a);
      }
    }
    __syncthreads();
    // waves' own lgkmcnt(0) drains before their next barrier, so reading buf here
    // is safe against the write to the same buf two iterations later.
#pragma unroll
    for (int ks = 0; ks < 2; ks++) {
      FragU af;
      af.u = *(const uint4*)(&pT[buf][w * 16 + (lane & 15)][kf + ks * 32]);
#pragma unroll
      for (int nt = 0; nt < 4; nt++) {
        FragU bfr;
        bfr.u = *(const uint4*)(vb + (size_t)(nt * 16 + (lane & 15)) * S + k0 + kf + ks * 32);
        o[nt] = __builtin_amdgcn_mfma_f32_16x16x32_bf16(af.v, bfr.v, o[nt], 0, 0, 0);
      }
    }
    buf ^= 1;
  }

  float* pOz = pO + (size_t)blockIdx.z * MROWS * DM;
#pragma unroll
  for (int nt = 0; nt < 4; nt++) {
#pragma unroll
    for (int r = 0; r < 4; r++) {
      int qg = q0 + w * 16 + (lane >> 4) * 4 + r;
      int col = h * 64 + nt * 16 + (lane & 15);
      pOz[((size_t)b * S + qg) * DM + col] = o[nt][r];
    }
  }
}

// ---------------- sum partial O -> bf16 concat -------------------------------
__global__ __launch_bounds__(256) void k_reduceO(const float* __restrict__ p0,
                                                  const float* __restrict__ p1,
                                                  unsigned short* __restrict__ conc) {
  size_t t = (size_t)blockIdx.x * 256 + threadIdx.x;
  float4 a = ((const float4*)p0)[t];
  float4 b = ((const float4*)p1)[t];
  union { unsigned short s[4]; uint2 u; } o;
  o.s[0] = f2bf(a.x + b.x);
  o.s[1] = f2bf(a.y + b.y);
  o.s[2] = f2bf(a.z + b.z);
  o.s[3] = f2bf(a.w + b.w);
  *(uint2*)(conc + t * 4) = o.u;
}

// ---------------- out projection: out = concat @ Wo + bo ---------------------
__global__ __launch_bounds__(256) void k_outproj(
    const unsigned short* __restrict__ concat, const unsigned short* __restrict__ wt,
    const float* __restrict__ bias, float* __restrict__ out) {
  const unsigned short* w = wt + (size_t)3 * DM * DM;
  int lane = threadIdx.x & 63, wv = threadIdx.x >> 6;
  int m0 = blockIdx.x * 64 + wv * 16;
  int n0 = blockIdx.y * 64;
  int kf = (lane >> 4) * 8;

  f32x4 acc[4] = {{0.f, 0.f, 0.f, 0.f}, {0.f, 0.f, 0.f, 0.f},
                  {0.f, 0.f, 0.f, 0.f}, {0.f, 0.f, 0.f, 0.f}};

  for (int kk0 = 0; kk0 < DM; kk0 += 32) {
    FragU af;
    af.u = *(const uint4*)(concat + (size_t)(m0 + (lane & 15)) * DM + kk0 + kf);
#pragma unroll
    for (int nt = 0; nt < 4; nt++) {
      FragU bfr;
      bfr.u = *(const uint4*)(w + (size_t)(n0 + nt * 16 + (lane & 15)) * DM + kk0 + kf);
      acc[nt] = __builtin_amdgcn_mfma_f32_16x16x32_bf16(af.v, bfr.v, acc[nt], 0, 0, 0);
    }
  }
#pragma unroll
  for (int nt = 0; nt < 4; nt++) {
#pragma unroll
    for (int r = 0; r < 4; r++) {
      int row = m0 + (lane >> 4) * 4 + r;
      int col = n0 + nt * 16 + (lane & 15);
      out[(size_t)row * DM + col] = acc[nt][r] + bias[col];
    }
  }
}

extern "C" void kernel_launch(void* const* d_in, const int* in_sizes, int n_in,
                              void* d_out, int out_size, void* d_ws, size_t ws_size,
                              hipStream_t stream) {
  (void)in_sizes; (void)n_in; (void)out_size; (void)ws_size;
  const float* v    = (const float*)d_in[0];
  const float* q    = (const float*)d_in[1];
  const float* k    = (const float*)d_in[2];
  const int*   mask = (const int*)d_in[3];
  const float* wq_w = (const float*)d_in[4];
  const float* wq_b = (const float*)d_in[5];
  const float* wk_w = (const float*)d_in[6];
  const float* wk_b = (const float*)d_in[7];
  const float* wv_w = (const float*)d_in[8];
  const float* wv_b = (const float*)d_in[9];
  const float* wo_w = (const float*)d_in[10];
  const float* wo_b = (const float*)d_in[11];

  char* ws = (char*)d_ws;
  size_t off = 0;
  auto alloc = [&](size_t bytes) {
    char* p = ws + off;
    off += (bytes + 255) & ~(size_t)255;
    return p;
  };
  unsigned short* wt   = (unsigned short*)alloc((size_t)4 * DM * DM * 2);   // 2 MB
  unsigned short* qbf  = (unsigned short*)alloc((size_t)MROWS * DM * 2);    // 4 MB
  unsigned short* kbf  = (unsigned short*)alloc((size_t)MROWS * DM * 2);    // 4 MB
  unsigned short* vbf  = (unsigned short*)alloc((size_t)MROWS * DM * 2);    // 4 MB
  unsigned short* qq   = (unsigned short*)alloc((size_t)BH * S * HD * 2);   // 4 MB
  unsigned short* kk2  = (unsigned short*)alloc((size_t)BH * S * HD * 2);   // 4 MB
  unsigned short* vvT  = (unsigned short*)alloc((size_t)BH * S * HD * 2);   // 4 MB
  unsigned*       mp   = (unsigned*)alloc((size_t)NB * S * QW * 4);         // 1 MB
  float*          Zs   = (float*)alloc((size_t)BH * S * 4);                 // 128 KB
  float*          pO   = (float*)alloc((size_t)2 * MROWS * DM * 4);         // 16.8 MB
  unsigned short* conc = (unsigned short*)alloc((size_t)MROWS * DM * 2);    // 4 MB

  float* out_final = (float*)d_out;
  float* out_attn  = (float*)d_out + (size_t)MROWS * DM;

  k_prep<<<dim3(4384), 256, 0, stream>>>(wq_w, wk_w, wv_w, wo_w, wt,
                                          q, k, v, qbf, kbf, vbf,
                                          mask, mp, Zs);
  k_proj<<<dim3(64, 8, 3), 256, 0, stream>>>(qbf, kbf, vbf, wt, wq_b, wk_b, wv_b,
                                              qq, kk2, vvT);
  k_softmax_z<<<dim3(32, 16, 2), 256, 0, stream>>>(qq, kk2, mp, Zs);
  k_attn<<<dim3(32, 16, 2), 256, 0, stream>>>(qq, kk2, vvT, mp, Zs, out_attn, pO);
  k_reduceO<<<dim3(2048), 256, 0, stream>>>(pO, pO + (size_t)MROWS * DM, conc);
  k_outproj<<<dim3(64, 8), 256, 0, stream>>>(conc, wt, wo_b, out_final);
}